// Round 6
// baseline (159.701 us; speedup 1.0000x reference)
//
#include <hip/hip_runtime.h>
#include <hip/hip_cooperative_groups.h>
#include <math.h>

namespace cg = cooperative_groups;

#define NTOK 2048
#define CC   128
#define CPP  16
#define HH   8
#define DHH  16
#define NQW  32
#define NKW  128
#define PADW 48
#define NBW  64

__device__ __forceinline__ float sigm(float x) { return 1.0f / (1.0f + expf(-x)); }

struct Params {
  const float *x1, *x2, *gamma_s, *Wg_ada, *bg_ada, *W_skip;
  const float *Wq, *Wk, *Wv, *Wg, *bg;
  const float *pair, *gamma_p, *beta_p, *W_pair;
  const float *Wo, *bo, *W_out, *b_out;
  float *qb, *kb, *vb, *gb, *obuf, *bias, *out;
};

// ---------------------------------------------------------------------------
// Mega kernel: 512 blocks x 256 threads, cooperative.
// Phase A: b<256 -> prep 8 rows (LN+adaLN+4 projections, in-LDS)
//          b>=256 -> bias for 8 tokens
// Phase B: 2 attention units (w,h,q-half) per block
// Phase C: out epilogue, 4 rows per block
// ---------------------------------------------------------------------------
__global__ __launch_bounds__(256, 2) void mega_kernel(Params P) {
  union SMem {
    struct { float sln[8][132], aln[8][132], as_[8][132]; } prep;   // 12.7 KB
    struct { float wp[CPP * HH], gp[CPP], bp[CPP]; } bia;           // tiny
    struct { float qs[16][20], ks[NKW][20], vs[NKW][20], bs[16][132]; } at; // 29.5 KB
    struct { float og[4][132], us[4][132]; } outp;                  // 4.2 KB
  };
  __shared__ SMem sm;
  cg::grid_group grid = cg::this_grid();
  const int b   = blockIdx.x;
  const int tid = threadIdx.x;

  // ============================ PHASE A ============================
  if (b < 256) {
    const int r0 = b * 8;
    // ---- LN of 8 rows: 32 lanes per row, float4 per lane ----
    {
      const int r = tid >> 5, t = tid & 31, c0 = t * 4;
      const int row = r0 + r;
      float4 v1 = *(const float4*)(P.x1 + (size_t)row * CC + c0);
      float4 v2 = *(const float4*)(P.x2 + (size_t)row * CC + c0);
      float s1 = v1.x + v1.y + v1.z + v1.w;
      float p1 = v1.x * v1.x + v1.y * v1.y + v1.z * v1.z + v1.w * v1.w;
      float s2 = v2.x + v2.y + v2.z + v2.w;
      float p2 = v2.x * v2.x + v2.y * v2.y + v2.z * v2.z + v2.w * v2.w;
#pragma unroll
      for (int m = 1; m < 32; m <<= 1) {
        s1 += __shfl_xor(s1, m); p1 += __shfl_xor(p1, m);
        s2 += __shfl_xor(s2, m); p2 += __shfl_xor(p2, m);
      }
      const float rc = 1.0f / 128.0f;
      float mu1 = s1 * rc, mu2 = s2 * rc;
      float rs1 = rsqrtf(p1 * rc - mu1 * mu1 + 1e-5f);
      float rs2 = rsqrtf(p2 * rc - mu2 * mu2 + 1e-5f);
      float4 gs = *(const float4*)(P.gamma_s + c0);
      float4 al, sl;
      al.x = (v1.x - mu1) * rs1; al.y = (v1.y - mu1) * rs1;
      al.z = (v1.z - mu1) * rs1; al.w = (v1.w - mu1) * rs1;
      sl.x = (v2.x - mu2) * rs2 * gs.x; sl.y = (v2.y - mu2) * rs2 * gs.y;
      sl.z = (v2.z - mu2) * rs2 * gs.z; sl.w = (v2.w - mu2) * rs2 * gs.w;
      *(float4*)(&sm.prep.aln[r][c0]) = al;
      *(float4*)(&sm.prep.sln[r][c0]) = sl;
    }
    __syncthreads();

    // ---- stage-1 adaLN GEMM: thread (rh, cg) -> 4 rows x 1 col ----
    {
      const int rh = tid >> 7, cg = tid & 127;
      float g0 = 0.f, g1 = 0.f, g2 = 0.f, g3 = 0.f;
      float s0 = 0.f, s1 = 0.f, s2 = 0.f, s3 = 0.f;
#pragma unroll 4
      for (int k4 = 0; k4 < 32; ++k4) {
        float4 a0 = *(const float4*)(&sm.prep.sln[rh * 4 + 0][k4 * 4]);
        float4 a1 = *(const float4*)(&sm.prep.sln[rh * 4 + 1][k4 * 4]);
        float4 a2 = *(const float4*)(&sm.prep.sln[rh * 4 + 2][k4 * 4]);
        float4 a3 = *(const float4*)(&sm.prep.sln[rh * 4 + 3][k4 * 4]);
#define S1STEP(AX, J) { \
        float wg = P.Wg_ada[(k4 * 4 + J) * CC + cg]; \
        float wk = P.W_skip[(k4 * 4 + J) * CC + cg]; \
        g0 = fmaf(a0.AX, wg, g0); g1 = fmaf(a1.AX, wg, g1); \
        g2 = fmaf(a2.AX, wg, g2); g3 = fmaf(a3.AX, wg, g3); \
        s0 = fmaf(a0.AX, wk, s0); s1 = fmaf(a1.AX, wk, s1); \
        s2 = fmaf(a2.AX, wk, s2); s3 = fmaf(a3.AX, wk, s3); }
        S1STEP(x, 0) S1STEP(y, 1) S1STEP(z, 2) S1STEP(w, 3)
#undef S1STEP
      }
      float bga = P.bg_ada[cg];
      float o0 = sigm(g0 + bga) * sm.prep.aln[rh * 4 + 0][cg] + s0;
      float o1 = sigm(g1 + bga) * sm.prep.aln[rh * 4 + 1][cg] + s1;
      float o2 = sigm(g2 + bga) * sm.prep.aln[rh * 4 + 2][cg] + s2;
      float o3 = sigm(g3 + bga) * sm.prep.aln[rh * 4 + 3][cg] + s3;
      __syncthreads();   // aln/sln reads done before as_ overwrites union? (as_ distinct) - keep order safe
      sm.prep.as_[rh * 4 + 0][cg] = o0;
      sm.prep.as_[rh * 4 + 1][cg] = o1;
      sm.prep.as_[rh * 4 + 2][cg] = o2;
      sm.prep.as_[rh * 4 + 3][cg] = o3;
    }
    __syncthreads();

    // ---- projections: wave m = matrix, lane -> 2 cols, 8 rows ----
    {
      const int m  = tid >> 6;
      const int l  = tid & 63;
      const int c0 = l * 2;
      const float* Wm = (m == 0) ? P.Wq : (m == 1) ? P.Wk : (m == 2) ? P.Wv : P.Wg;
      float2 c0_ = {0.f, 0.f}, c1_ = {0.f, 0.f}, c2_ = {0.f, 0.f}, c3_ = {0.f, 0.f};
      float2 c4_ = {0.f, 0.f}, c5_ = {0.f, 0.f}, c6_ = {0.f, 0.f}, c7_ = {0.f, 0.f};
#pragma unroll 2
      for (int k4 = 0; k4 < 32; ++k4) {
        float4 ra0 = *(const float4*)(&sm.prep.as_[0][k4 * 4]);
        float4 ra1 = *(const float4*)(&sm.prep.as_[1][k4 * 4]);
        float4 ra2 = *(const float4*)(&sm.prep.as_[2][k4 * 4]);
        float4 ra3 = *(const float4*)(&sm.prep.as_[3][k4 * 4]);
        float4 ra4 = *(const float4*)(&sm.prep.as_[4][k4 * 4]);
        float4 ra5 = *(const float4*)(&sm.prep.as_[5][k4 * 4]);
        float4 ra6 = *(const float4*)(&sm.prep.as_[6][k4 * 4]);
        float4 ra7 = *(const float4*)(&sm.prep.as_[7][k4 * 4]);
#define PJSTEP(AX, J) { \
        float2 wv = *(const float2*)(Wm + (k4 * 4 + J) * CC + c0); \
        c0_.x = fmaf(ra0.AX, wv.x, c0_.x); c0_.y = fmaf(ra0.AX, wv.y, c0_.y); \
        c1_.x = fmaf(ra1.AX, wv.x, c1_.x); c1_.y = fmaf(ra1.AX, wv.y, c1_.y); \
        c2_.x = fmaf(ra2.AX, wv.x, c2_.x); c2_.y = fmaf(ra2.AX, wv.y, c2_.y); \
        c3_.x = fmaf(ra3.AX, wv.x, c3_.x); c3_.y = fmaf(ra3.AX, wv.y, c3_.y); \
        c4_.x = fmaf(ra4.AX, wv.x, c4_.x); c4_.y = fmaf(ra4.AX, wv.y, c4_.y); \
        c5_.x = fmaf(ra5.AX, wv.x, c5_.x); c5_.y = fmaf(ra5.AX, wv.y, c5_.y); \
        c6_.x = fmaf(ra6.AX, wv.x, c6_.x); c6_.y = fmaf(ra6.AX, wv.y, c6_.y); \
        c7_.x = fmaf(ra7.AX, wv.x, c7_.x); c7_.y = fmaf(ra7.AX, wv.y, c7_.y); }
        PJSTEP(x, 0) PJSTEP(y, 1) PJSTEP(z, 2) PJSTEP(w, 3)
#undef PJSTEP
      }
      if (m == 0) {
#define QST(I, CI) { float2 r; r.x = CI.x * 0.25f; r.y = CI.y * 0.25f; \
        *(float2*)(P.qb + (size_t)(r0 + I) * CC + c0) = r; }
        QST(0, c0_) QST(1, c1_) QST(2, c2_) QST(3, c3_)
        QST(4, c4_) QST(5, c5_) QST(6, c6_) QST(7, c7_)
#undef QST
      } else if (m == 1) {
#define KST(I, CI) *(float2*)(P.kb + (size_t)(r0 + I) * CC + c0) = CI;
        KST(0, c0_) KST(1, c1_) KST(2, c2_) KST(3, c3_)
        KST(4, c4_) KST(5, c5_) KST(6, c6_) KST(7, c7_)
#undef KST
      } else if (m == 2) {
#define VST(I, CI) *(float2*)(P.vb + (size_t)(r0 + I) * CC + c0) = CI;
        VST(0, c0_) VST(1, c1_) VST(2, c2_) VST(3, c3_)
        VST(4, c4_) VST(5, c5_) VST(6, c6_) VST(7, c7_)
#undef VST
      } else {
        float2 bgv = *(const float2*)(P.bg + c0);
#define GST(I, CI) { float2 r; r.x = sigm(CI.x + bgv.x); r.y = sigm(CI.y + bgv.y); \
        *(float2*)(P.gb + (size_t)(r0 + I) * CC + c0) = r; }
        GST(0, c0_) GST(1, c1_) GST(2, c2_) GST(3, c3_)
        GST(4, c4_) GST(5, c5_) GST(6, c6_) GST(7, c7_)
#undef GST
      }
    }
  } else {
    // ---- bias: 8 tokens for this block ----
    if (tid < CPP * HH) sm.bia.wp[tid] = P.W_pair[tid];
    if (tid < CPP) { sm.bia.gp[tid] = P.gamma_p[tid]; sm.bia.bp[tid] = P.beta_p[tid]; }
    __syncthreads();

#pragma unroll
    for (int it = 0; it < 4; ++it) {
      const int i  = (b - 256) * 8 + it * 2 + (tid >> 7);   // token 0..2047
      const int w  = i >> 5;
      const int qq = i & 31;
      const int k  = tid & 127;
      const int j  = w * NQW + k - PADW;

      float bh[HH];
      if (j >= 0 && j < NTOK) {
        const float* p = P.pair + ((size_t)i * NTOK + j) * CPP;
        float x[CPP];
#pragma unroll
        for (int u4 = 0; u4 < CPP; u4 += 4) {
          float4 v = *(const float4*)(p + u4);
          x[u4] = v.x; x[u4 + 1] = v.y; x[u4 + 2] = v.z; x[u4 + 3] = v.w;
        }
        float s = 0.f;
#pragma unroll
        for (int c = 0; c < CPP; ++c) s += x[c];
        float mu = s * (1.0f / CPP);
        float vv = 0.f;
#pragma unroll
        for (int c = 0; c < CPP; ++c) { float d = x[c] - mu; vv = fmaf(d, d, vv); }
        float rs = rsqrtf(vv * (1.0f / CPP) + 1e-5f);
#pragma unroll
        for (int h = 0; h < HH; ++h) bh[h] = 0.f;
#pragma unroll
        for (int c = 0; c < CPP; ++c) {
          float y = (x[c] - mu) * rs * sm.bia.gp[c] + sm.bia.bp[c];
#pragma unroll
          for (int h = 0; h < HH; ++h) bh[h] = fmaf(y, sm.bia.wp[c * HH + h], bh[h]);
        }
      } else {
#pragma unroll
        for (int h = 0; h < HH; ++h) bh[h] = -10000.0f;
      }
#pragma unroll
      for (int h = 0; h < HH; ++h)
        P.bias[((size_t)((w * HH + h) * NQW + qq)) * NKW + k] = bh[h];
    }
  }

  grid.sync();

  // ============================ PHASE B ============================
#pragma unroll 1
  for (int rep = 0; rep < 2; ++rep) {
    const int u  = b * 2 + rep;
    const int w  = u >> 4;
    const int h  = (u >> 1) & 7;
    const int qh = u & 1;

    if (tid < 64) {
      int qr = tid >> 2, c4 = (tid & 3) * 4;
      float4 v = *(const float4*)(P.qb + (size_t)(w * NQW + qh * 16 + qr) * CC + h * DHH + c4);
      *(float4*)(&sm.at.qs[qr][c4]) = v;
    }
    {
      int kr = tid >> 1, c8 = (tid & 1) * 8;
      int j = w * NQW + kr - PADW;
      float4 k0 = make_float4(0.f, 0.f, 0.f, 0.f), k1 = k0, v0 = k0, v1 = k0;
      if (j >= 0 && j < NTOK) {
        const float* kp = P.kb + (size_t)j * CC + h * DHH + c8;
        const float* vp = P.vb + (size_t)j * CC + h * DHH + c8;
        k0 = *(const float4*)(kp);     k1 = *(const float4*)(kp + 4);
        v0 = *(const float4*)(vp);     v1 = *(const float4*)(vp + 4);
      }
      *(float4*)(&sm.at.ks[kr][c8])     = k0;
      *(float4*)(&sm.at.ks[kr][c8 + 4]) = k1;
      *(float4*)(&sm.at.vs[kr][c8])     = v0;
      *(float4*)(&sm.at.vs[kr][c8 + 4]) = v1;
    }
    {
      const float* bt = P.bias + (size_t)(w * HH + h) * NQW * NKW + (size_t)qh * 16 * NKW;
      int qr = tid >> 4, k8 = (tid & 15) * 8;
      float4 b0 = *(const float4*)(bt + qr * NKW + k8);
      float4 b1 = *(const float4*)(bt + qr * NKW + k8 + 4);
      *(float4*)(&sm.at.bs[qr][k8])     = b0;
      *(float4*)(&sm.at.bs[qr][k8 + 4]) = b1;
    }
    __syncthreads();

    const int qr = tid >> 4;   // 0..15
    const int t  = tid & 15;   // 0..15
    float4 q0 = *(float4*)(&sm.at.qs[qr][0]);
    float4 q1 = *(float4*)(&sm.at.qs[qr][4]);
    float4 q2 = *(float4*)(&sm.at.qs[qr][8]);
    float4 q3 = *(float4*)(&sm.at.qs[qr][12]);

    float l[8];
#pragma unroll
    for (int i = 0; i < 8; ++i) {
      int k = t + 16 * i;
      const float* kr_ = &sm.at.ks[k][0];
      float4 k0 = *(const float4*)(kr_);
      float4 k1 = *(const float4*)(kr_ + 4);
      float4 k2 = *(const float4*)(kr_ + 8);
      float4 k3 = *(const float4*)(kr_ + 12);
      float d = 0.f;
      d = fmaf(q0.x, k0.x, d); d = fmaf(q0.y, k0.y, d);
      d = fmaf(q0.z, k0.z, d); d = fmaf(q0.w, k0.w, d);
      d = fmaf(q1.x, k1.x, d); d = fmaf(q1.y, k1.y, d);
      d = fmaf(q1.z, k1.z, d); d = fmaf(q1.w, k1.w, d);
      d = fmaf(q2.x, k2.x, d); d = fmaf(q2.y, k2.y, d);
      d = fmaf(q2.z, k2.z, d); d = fmaf(q2.w, k2.w, d);
      d = fmaf(q3.x, k3.x, d); d = fmaf(q3.y, k3.y, d);
      d = fmaf(q3.z, k3.z, d); d = fmaf(q3.w, k3.w, d);
      l[i] = d + sm.at.bs[qr][k];
    }

    float m0 = l[0];
#pragma unroll
    for (int i = 1; i < 8; ++i) m0 = fmaxf(m0, l[i]);
    m0 = fmaxf(m0, __shfl_xor(m0, 1));
    m0 = fmaxf(m0, __shfl_xor(m0, 2));
    m0 = fmaxf(m0, __shfl_xor(m0, 4));
    m0 = fmaxf(m0, __shfl_xor(m0, 8));
    float s = 0.f;
    float p[8];
#pragma unroll
    for (int i = 0; i < 8; ++i) { p[i] = expf(l[i] - m0); s += p[i]; }
    s += __shfl_xor(s, 1);
    s += __shfl_xor(s, 2);
    s += __shfl_xor(s, 4);
    s += __shfl_xor(s, 8);
    float inv = 1.0f / s;
#pragma unroll
    for (int i = 0; i < 8; ++i) p[i] *= inv;

    float o[16];
#pragma unroll
    for (int d = 0; d < 16; ++d) o[d] = 0.f;
#pragma unroll
    for (int i = 0; i < 8; ++i) {
      int k = t + 16 * i;
      const float* vr = &sm.at.vs[k][0];
      float4 v0 = *(const float4*)(vr);
      float4 v1 = *(const float4*)(vr + 4);
      float4 v2 = *(const float4*)(vr + 8);
      float4 v3 = *(const float4*)(vr + 12);
      float pa = p[i];
      o[0]  = fmaf(pa, v0.x, o[0]);  o[1]  = fmaf(pa, v0.y, o[1]);
      o[2]  = fmaf(pa, v0.z, o[2]);  o[3]  = fmaf(pa, v0.w, o[3]);
      o[4]  = fmaf(pa, v1.x, o[4]);  o[5]  = fmaf(pa, v1.y, o[5]);
      o[6]  = fmaf(pa, v1.z, o[6]);  o[7]  = fmaf(pa, v1.w, o[7]);
      o[8]  = fmaf(pa, v2.x, o[8]);  o[9]  = fmaf(pa, v2.y, o[9]);
      o[10] = fmaf(pa, v2.z, o[10]); o[11] = fmaf(pa, v2.w, o[11]);
      o[12] = fmaf(pa, v3.x, o[12]); o[13] = fmaf(pa, v3.y, o[13]);
      o[14] = fmaf(pa, v3.z, o[14]); o[15] = fmaf(pa, v3.w, o[15]);
    }
#pragma unroll
    for (int d = 0; d < 16; ++d) {
#pragma unroll
      for (int m = 1; m < 16; m <<= 1) o[d] += __shfl_xor(o[d], m);
    }
    float wsel = 0.f;
#pragma unroll
    for (int d = 0; d < 16; ++d) wsel = (t == d) ? o[d] : wsel;
    P.obuf[(size_t)(w * NQW + qh * 16 + qr) * CC + h * DHH + t] = wsel;
    __syncthreads();   // protect LDS before next rep re-stages
  }

  grid.sync();

  // ============================ PHASE C ============================
  {
    const int r0 = b * 4;
    {
      const int r = tid >> 6, t = tid & 63, c0 = t * 2;
      float2 o2 = *(const float2*)(P.obuf + (size_t)(r0 + r) * CC + c0);
      float2 g2 = *(const float2*)(P.gb   + (size_t)(r0 + r) * CC + c0);
      sm.outp.og[r][c0]     = o2.x * g2.x;
      sm.outp.og[r][c0 + 1] = o2.y * g2.y;
    }
    __syncthreads();

    const int rh = tid >> 7, cg = tid & 127;
    const int ra = rh * 2, rb = rh * 2 + 1;
    float u0 = 0.f, u1 = 0.f;
#pragma unroll 4
    for (int k4 = 0; k4 < 32; ++k4) {
      float4 a0 = *(const float4*)(&sm.outp.og[ra][k4 * 4]);
      float4 a1 = *(const float4*)(&sm.outp.og[rb][k4 * 4]);
#define C1STEP(AX, J) { \
      float wv = P.Wo[(k4 * 4 + J) * CC + cg]; \
      u0 = fmaf(a0.AX, wv, u0); u1 = fmaf(a1.AX, wv, u1); }
      C1STEP(x, 0) C1STEP(y, 1) C1STEP(z, 2) C1STEP(w, 3)
#undef C1STEP
    }
    float bov = P.bo[cg];
    u0 += bov; u1 += bov;
    sm.outp.us[ra][cg] = u0;
    sm.outp.us[rb][cg] = u1;
    __syncthreads();

    float a0s = 0.f, a1s = 0.f;
#pragma unroll 4
    for (int k4 = 0; k4 < 32; ++k4) {
      float4 a0 = *(const float4*)(&sm.outp.us[ra][k4 * 4]);
      float4 a1 = *(const float4*)(&sm.outp.us[rb][k4 * 4]);
#define C2STEP(AX, J) { \
      float wv = P.W_out[(k4 * 4 + J) * CC + cg]; \
      a0s = fmaf(a0.AX, wv, a0s); a1s = fmaf(a1.AX, wv, a1s); }
      C2STEP(x, 0) C2STEP(y, 1) C2STEP(z, 2) C2STEP(w, 3)
#undef C2STEP
    }
    float b2 = P.b_out[cg];
    P.out[(size_t)(r0 + ra) * CC + cg] = sigm(a0s + b2) * u0;
    P.out[(size_t)(r0 + rb) * CC + cg] = sigm(a1s + b2) * u1;
  }
}

// ---------------------------------------------------------------------------
extern "C" void kernel_launch(void* const* d_in, const int* in_sizes, int n_in,
                              void* d_out, int out_size, void* d_ws, size_t ws_size,
                              hipStream_t stream) {
  (void)in_sizes; (void)n_in; (void)out_size; (void)ws_size;
  float* ws = (float*)d_ws;
  const size_t NC = (size_t)NTOK * CC;   // 262144

  Params P;
  P.x1      = (const float*)d_in[0];
  P.x2      = (const float*)d_in[1];
  P.pair    = (const float*)d_in[2];
  P.gamma_s = (const float*)d_in[3];
  P.Wg_ada  = (const float*)d_in[4];
  P.bg_ada  = (const float*)d_in[5];
  P.W_skip  = (const float*)d_in[6];
  P.gamma_p = (const float*)d_in[7];
  P.beta_p  = (const float*)d_in[8];
  P.W_pair  = (const float*)d_in[9];
  P.Wq      = (const float*)d_in[10];
  P.Wk      = (const float*)d_in[11];
  P.Wv      = (const float*)d_in[12];
  P.Wg      = (const float*)d_in[13];
  P.bg      = (const float*)d_in[14];
  P.Wo      = (const float*)d_in[15];
  P.bo      = (const float*)d_in[16];
  P.W_out   = (const float*)d_in[17];
  P.b_out   = (const float*)d_in[18];
  P.qb   = ws;
  P.kb   = ws + NC;
  P.vb   = ws + 2 * NC;
  P.gb   = ws + 3 * NC;
  P.obuf = ws + 4 * NC;
  P.bias = ws + 5 * NC;                 // 2097152 floats
  P.out  = (float*)d_out;

  void* kargs[] = { (void*)&P };
  hipLaunchCooperativeKernel((const void*)mega_kernel, dim3(512), dim3(256),
                             kargs, 0, stream);
}

// Round 7
// 58.839 us; speedup vs baseline: 2.7142x; 2.7142x over previous
//
#include <hip/hip_runtime.h>
#include <math.h>

#define NTOK 2048
#define CC   128
#define CPP  16
#define HH   8
#define DHH  16
#define NQW  32
#define NKW  128
#define PADW 48
#define NBW  64

__device__ __forceinline__ float sigm(float x) { return 1.0f / (1.0f + expf(-x)); }

// ---------------------------------------------------------------------------
// K1: blocks [0,256): LN + adaLN GEMM (R2C2) + 4 projections (R4C4), 8 rows.
//     blocks [256,512): bias for 8 tokens each.
// ---------------------------------------------------------------------------
__global__ __launch_bounds__(256) void k1_fused(
    const float* __restrict__ x1, const float* __restrict__ x2,
    const float* __restrict__ gamma_s,
    const float* __restrict__ Wg_ada, const float* __restrict__ bg_ada,
    const float* __restrict__ W_skip,
    const float* __restrict__ Wq, const float* __restrict__ Wk,
    const float* __restrict__ Wv, const float* __restrict__ Wg,
    const float* __restrict__ bg,
    const float* __restrict__ pair,
    const float* __restrict__ gamma_p, const float* __restrict__ beta_p,
    const float* __restrict__ W_pair,
    float* __restrict__ qb, float* __restrict__ kb,
    float* __restrict__ vb, float* __restrict__ gb,
    float* __restrict__ bias)
{
  const int b   = blockIdx.x;
  const int tid = threadIdx.x;

  if (b < 256) {
    __shared__ float sln[8][132];
    __shared__ float aln[8][132];
    __shared__ float as_[8][132];
    const int r0 = b * 8;

    // ---- LN of 8 rows: 32 lanes per row, float4 per lane ----
    {
      const int r = tid >> 5, t = tid & 31, c0 = t * 4;
      const int row = r0 + r;
      float4 v1 = *(const float4*)(x1 + (size_t)row * CC + c0);
      float4 v2 = *(const float4*)(x2 + (size_t)row * CC + c0);
      float s1 = v1.x + v1.y + v1.z + v1.w;
      float p1 = v1.x * v1.x + v1.y * v1.y + v1.z * v1.z + v1.w * v1.w;
      float s2 = v2.x + v2.y + v2.z + v2.w;
      float p2 = v2.x * v2.x + v2.y * v2.y + v2.z * v2.z + v2.w * v2.w;
#pragma unroll
      for (int m = 1; m < 32; m <<= 1) {
        s1 += __shfl_xor(s1, m); p1 += __shfl_xor(p1, m);
        s2 += __shfl_xor(s2, m); p2 += __shfl_xor(p2, m);
      }
      const float rc = 1.0f / 128.0f;
      float mu1 = s1 * rc, mu2 = s2 * rc;
      float rs1 = rsqrtf(p1 * rc - mu1 * mu1 + 1e-5f);
      float rs2 = rsqrtf(p2 * rc - mu2 * mu2 + 1e-5f);
      float4 gs = *(const float4*)(gamma_s + c0);
      float4 al, sl;
      al.x = (v1.x - mu1) * rs1; al.y = (v1.y - mu1) * rs1;
      al.z = (v1.z - mu1) * rs1; al.w = (v1.w - mu1) * rs1;
      sl.x = (v2.x - mu2) * rs2 * gs.x; sl.y = (v2.y - mu2) * rs2 * gs.y;
      sl.z = (v2.z - mu2) * rs2 * gs.z; sl.w = (v2.w - mu2) * rs2 * gs.w;
      *(float4*)(&aln[r][c0]) = al;
      *(float4*)(&sln[r][c0]) = sl;
    }
    __syncthreads();

    // ---- stage-1 adaLN GEMM: R2C2, wave rg owns rows {2rg,2rg+1} ----
    {
      const int rg = tid >> 6;        // 0..3
      const int cg = tid & 63;
      const int c0 = cg * 2;
      const int ra = rg * 2, rb = rg * 2 + 1;
      float g00 = 0.f, g01 = 0.f, g10 = 0.f, g11 = 0.f;
      float s00 = 0.f, s01 = 0.f, s10 = 0.f, s11 = 0.f;
#pragma unroll 4
      for (int k4 = 0; k4 < 32; ++k4) {
        float4 a0 = *(const float4*)(&sln[ra][k4 * 4]);
        float4 a1 = *(const float4*)(&sln[rb][k4 * 4]);
#define S1STEP(AX, J) { \
        float2 wg = *(const float2*)(Wg_ada + (k4 * 4 + J) * CC + c0); \
        float2 wk = *(const float2*)(W_skip + (k4 * 4 + J) * CC + c0); \
        g00 = fmaf(a0.AX, wg.x, g00); g01 = fmaf(a0.AX, wg.y, g01); \
        g10 = fmaf(a1.AX, wg.x, g10); g11 = fmaf(a1.AX, wg.y, g11); \
        s00 = fmaf(a0.AX, wk.x, s00); s01 = fmaf(a0.AX, wk.y, s01); \
        s10 = fmaf(a1.AX, wk.x, s10); s11 = fmaf(a1.AX, wk.y, s11); }
        S1STEP(x, 0) S1STEP(y, 1) S1STEP(z, 2) S1STEP(w, 3)
#undef S1STEP
      }
      float2 bga = *(const float2*)(bg_ada + c0);
      as_[ra][c0]     = sigm(g00 + bga.x) * aln[ra][c0]     + s00;
      as_[ra][c0 + 1] = sigm(g01 + bga.y) * aln[ra][c0 + 1] + s01;
      as_[rb][c0]     = sigm(g10 + bga.x) * aln[rb][c0]     + s10;
      as_[rb][c0 + 1] = sigm(g11 + bga.y) * aln[rb][c0 + 1] + s11;
    }
    __syncthreads();

    // ---- projections: wave m = matrix; R4C4 (4 rows x 4 cols/thread) ----
    {
      const int m   = tid >> 6;
      const int l   = tid & 63;
      const int rg2 = l >> 5;          // 0/1 -> rows 4rg2..+3
      const int cl  = l & 31;
      const int c0  = cl * 4;
      const int rb0 = rg2 * 4;
      const float* Wm = (m == 0) ? Wq : (m == 1) ? Wk : (m == 2) ? Wv : Wg;
      float4 o0 = {0.f,0.f,0.f,0.f}, o1 = o0, o2 = o0, o3 = o0;
#pragma unroll 4
      for (int k4 = 0; k4 < 32; ++k4) {
        float4 a0 = *(const float4*)(&as_[rb0 + 0][k4 * 4]);
        float4 a1 = *(const float4*)(&as_[rb0 + 1][k4 * 4]);
        float4 a2 = *(const float4*)(&as_[rb0 + 2][k4 * 4]);
        float4 a3 = *(const float4*)(&as_[rb0 + 3][k4 * 4]);
#define PJSTEP(AX, J) { \
        float4 wv = *(const float4*)(Wm + (k4 * 4 + J) * CC + c0); \
        o0.x = fmaf(a0.AX, wv.x, o0.x); o0.y = fmaf(a0.AX, wv.y, o0.y); \
        o0.z = fmaf(a0.AX, wv.z, o0.z); o0.w = fmaf(a0.AX, wv.w, o0.w); \
        o1.x = fmaf(a1.AX, wv.x, o1.x); o1.y = fmaf(a1.AX, wv.y, o1.y); \
        o1.z = fmaf(a1.AX, wv.z, o1.z); o1.w = fmaf(a1.AX, wv.w, o1.w); \
        o2.x = fmaf(a2.AX, wv.x, o2.x); o2.y = fmaf(a2.AX, wv.y, o2.y); \
        o2.z = fmaf(a2.AX, wv.z, o2.z); o2.w = fmaf(a2.AX, wv.w, o2.w); \
        o3.x = fmaf(a3.AX, wv.x, o3.x); o3.y = fmaf(a3.AX, wv.y, o3.y); \
        o3.z = fmaf(a3.AX, wv.z, o3.z); o3.w = fmaf(a3.AX, wv.w, o3.w); }
        PJSTEP(x, 0) PJSTEP(y, 1) PJSTEP(z, 2) PJSTEP(w, 3)
#undef PJSTEP
      }
      if (m == 0) {
        o0.x *= 0.25f; o0.y *= 0.25f; o0.z *= 0.25f; o0.w *= 0.25f;
        o1.x *= 0.25f; o1.y *= 0.25f; o1.z *= 0.25f; o1.w *= 0.25f;
        o2.x *= 0.25f; o2.y *= 0.25f; o2.z *= 0.25f; o2.w *= 0.25f;
        o3.x *= 0.25f; o3.y *= 0.25f; o3.z *= 0.25f; o3.w *= 0.25f;
        *(float4*)(qb + (size_t)(r0 + rb0 + 0) * CC + c0) = o0;
        *(float4*)(qb + (size_t)(r0 + rb0 + 1) * CC + c0) = o1;
        *(float4*)(qb + (size_t)(r0 + rb0 + 2) * CC + c0) = o2;
        *(float4*)(qb + (size_t)(r0 + rb0 + 3) * CC + c0) = o3;
      } else if (m == 1) {
        *(float4*)(kb + (size_t)(r0 + rb0 + 0) * CC + c0) = o0;
        *(float4*)(kb + (size_t)(r0 + rb0 + 1) * CC + c0) = o1;
        *(float4*)(kb + (size_t)(r0 + rb0 + 2) * CC + c0) = o2;
        *(float4*)(kb + (size_t)(r0 + rb0 + 3) * CC + c0) = o3;
      } else if (m == 2) {
        *(float4*)(vb + (size_t)(r0 + rb0 + 0) * CC + c0) = o0;
        *(float4*)(vb + (size_t)(r0 + rb0 + 1) * CC + c0) = o1;
        *(float4*)(vb + (size_t)(r0 + rb0 + 2) * CC + c0) = o2;
        *(float4*)(vb + (size_t)(r0 + rb0 + 3) * CC + c0) = o3;
      } else {
        float4 bgv = *(const float4*)(bg + c0);
        float4 t0, t1, t2, t3;
        t0.x = sigm(o0.x + bgv.x); t0.y = sigm(o0.y + bgv.y);
        t0.z = sigm(o0.z + bgv.z); t0.w = sigm(o0.w + bgv.w);
        t1.x = sigm(o1.x + bgv.x); t1.y = sigm(o1.y + bgv.y);
        t1.z = sigm(o1.z + bgv.z); t1.w = sigm(o1.w + bgv.w);
        t2.x = sigm(o2.x + bgv.x); t2.y = sigm(o2.y + bgv.y);
        t2.z = sigm(o2.z + bgv.z); t2.w = sigm(o2.w + bgv.w);
        t3.x = sigm(o3.x + bgv.x); t3.y = sigm(o3.y + bgv.y);
        t3.z = sigm(o3.z + bgv.z); t3.w = sigm(o3.w + bgv.w);
        *(float4*)(gb + (size_t)(r0 + rb0 + 0) * CC + c0) = t0;
        *(float4*)(gb + (size_t)(r0 + rb0 + 1) * CC + c0) = t1;
        *(float4*)(gb + (size_t)(r0 + rb0 + 2) * CC + c0) = t2;
        *(float4*)(gb + (size_t)(r0 + rb0 + 3) * CC + c0) = t3;
      }
    }
  } else {
    __shared__ float wp[CPP * HH];
    __shared__ float gp[CPP];
    __shared__ float bp[CPP];
    if (tid < CPP * HH) wp[tid] = W_pair[tid];
    if (tid < CPP) { gp[tid] = gamma_p[tid]; bp[tid] = beta_p[tid]; }
    __syncthreads();

#pragma unroll
    for (int it = 0; it < 4; ++it) {
      const int i  = (b - 256) * 8 + it * 2 + (tid >> 7);   // token 0..2047
      const int w  = i >> 5;
      const int qq = i & 31;
      const int k  = tid & 127;
      const int j  = w * NQW + k - PADW;

      float bh[HH];
      if (j >= 0 && j < NTOK) {
        const float* p = pair + ((size_t)i * NTOK + j) * CPP;
        float x[CPP];
#pragma unroll
        for (int u4 = 0; u4 < CPP; u4 += 4) {
          float4 v = *(const float4*)(p + u4);
          x[u4] = v.x; x[u4 + 1] = v.y; x[u4 + 2] = v.z; x[u4 + 3] = v.w;
        }
        float s = 0.f;
#pragma unroll
        for (int c = 0; c < CPP; ++c) s += x[c];
        float mu = s * (1.0f / CPP);
        float vv = 0.f;
#pragma unroll
        for (int c = 0; c < CPP; ++c) { float d = x[c] - mu; vv = fmaf(d, d, vv); }
        float rs = rsqrtf(vv * (1.0f / CPP) + 1e-5f);
#pragma unroll
        for (int h = 0; h < HH; ++h) bh[h] = 0.f;
#pragma unroll
        for (int c = 0; c < CPP; ++c) {
          float y = (x[c] - mu) * rs * gp[c] + bp[c];
#pragma unroll
          for (int h = 0; h < HH; ++h) bh[h] = fmaf(y, wp[c * HH + h], bh[h]);
        }
      } else {
#pragma unroll
        for (int h = 0; h < HH; ++h) bh[h] = -10000.0f;
      }
#pragma unroll
      for (int h = 0; h < HH; ++h)
        bias[((size_t)((w * HH + h) * NQW + qq)) * NKW + k] = bh[h];
    }
  }
}

// ---------------------------------------------------------------------------
// K2: attention per (window, head). 512 blocks x 256 threads.
// thread = (qg 0..15, t 0..15): owns q-rows {2qg,2qg+1}, k-cols {t+16*i}.
// (round-3 kernel, verbatim — proven)
// ---------------------------------------------------------------------------
__global__ __launch_bounds__(256) void attn_kernel(
    const float* __restrict__ qb, const float* __restrict__ kb,
    const float* __restrict__ vb, const float* __restrict__ bias,
    float* __restrict__ ob)
{
  __shared__ float qs[NQW][20];
  __shared__ float ks[NKW][20];
  __shared__ float vs[NKW][20];
  __shared__ float bs[NQW][132];
  const int w   = blockIdx.x >> 3;
  const int h   = blockIdx.x & 7;
  const int tid = threadIdx.x;

  if (tid < 128) {
    int qr = tid >> 2, c4 = (tid & 3) * 4;
    float4 v = *(const float4*)(qb + (size_t)(w * NQW + qr) * CC + h * DHH + c4);
    *(float4*)(&qs[qr][c4]) = v;
  }
#pragma unroll
  for (int it = 0; it < 2; ++it) {
    int idx = tid + it * 256;          // 0..511
    int kr = idx >> 2, c4 = (idx & 3) * 4;
    int j = w * NQW + kr - PADW;
    float4 kv = make_float4(0.f, 0.f, 0.f, 0.f);
    float4 vv = make_float4(0.f, 0.f, 0.f, 0.f);
    if (j >= 0 && j < NTOK) {
      kv = *(const float4*)(kb + (size_t)j * CC + h * DHH + c4);
      vv = *(const float4*)(vb + (size_t)j * CC + h * DHH + c4);
    }
    *(float4*)(&ks[kr][c4]) = kv;
    *(float4*)(&vs[kr][c4]) = vv;
  }
  const float* bt = bias + (size_t)(w * HH + h) * NQW * NKW;
#pragma unroll
  for (int it = 0; it < 4; ++it) {
    int idx = tid + it * 256;          // 0..1023 float4 units
    int qr = idx >> 5, k4 = (idx & 31) * 4;
    float4 bv = *(const float4*)(bt + qr * NKW + k4);
    *(float4*)(&bs[qr][k4]) = bv;
  }
  __syncthreads();

  const int qg = tid >> 4;   // 0..15
  const int t  = tid & 15;   // 0..15
  const int r0 = qg * 2, r1 = r0 + 1;

  float4 qa0 = *(float4*)(&qs[r0][0]);
  float4 qa1 = *(float4*)(&qs[r0][4]);
  float4 qa2 = *(float4*)(&qs[r0][8]);
  float4 qa3 = *(float4*)(&qs[r0][12]);
  float4 qb0 = *(float4*)(&qs[r1][0]);
  float4 qb1 = *(float4*)(&qs[r1][4]);
  float4 qb2 = *(float4*)(&qs[r1][8]);
  float4 qb3 = *(float4*)(&qs[r1][12]);

  float l0[8], l1[8];
#pragma unroll
  for (int i = 0; i < 8; ++i) {
    int k = t + 16 * i;
    const float* kr = &ks[k][0];
    float4 k0 = *(const float4*)(kr);
    float4 k1 = *(const float4*)(kr + 4);
    float4 k2 = *(const float4*)(kr + 8);
    float4 k3 = *(const float4*)(kr + 12);
    float da = 0.f, db = 0.f;
    da = fmaf(qa0.x, k0.x, da); da = fmaf(qa0.y, k0.y, da);
    da = fmaf(qa0.z, k0.z, da); da = fmaf(qa0.w, k0.w, da);
    da = fmaf(qa1.x, k1.x, da); da = fmaf(qa1.y, k1.y, da);
    da = fmaf(qa1.z, k1.z, da); da = fmaf(qa1.w, k1.w, da);
    da = fmaf(qa2.x, k2.x, da); da = fmaf(qa2.y, k2.y, da);
    da = fmaf(qa2.z, k2.z, da); da = fmaf(qa2.w, k2.w, da);
    da = fmaf(qa3.x, k3.x, da); da = fmaf(qa3.y, k3.y, da);
    da = fmaf(qa3.z, k3.z, da); da = fmaf(qa3.w, k3.w, da);
    db = fmaf(qb0.x, k0.x, db); db = fmaf(qb0.y, k0.y, db);
    db = fmaf(qb0.z, k0.z, db); db = fmaf(qb0.w, k0.w, db);
    db = fmaf(qb1.x, k1.x, db); db = fmaf(qb1.y, k1.y, db);
    db = fmaf(qb1.z, k1.z, db); db = fmaf(qb1.w, k1.w, db);
    db = fmaf(qb2.x, k2.x, db); db = fmaf(qb2.y, k2.y, db);
    db = fmaf(qb2.z, k2.z, db); db = fmaf(qb2.w, k2.w, db);
    db = fmaf(qb3.x, k3.x, db); db = fmaf(qb3.y, k3.y, db);
    db = fmaf(qb3.z, k3.z, db); db = fmaf(qb3.w, k3.w, db);
    l0[i] = da + bs[r0][k];
    l1[i] = db + bs[r1][k];
  }

  float m0 = l0[0], m1 = l1[0];
#pragma unroll
  for (int i = 1; i < 8; ++i) { m0 = fmaxf(m0, l0[i]); m1 = fmaxf(m1, l1[i]); }
#pragma unroll
  for (int m = 1; m < 16; m <<= 1) {
    m0 = fmaxf(m0, __shfl_xor(m0, m));
    m1 = fmaxf(m1, __shfl_xor(m1, m));
  }
  float s0 = 0.f, s1 = 0.f;
  float p0[8], p1[8];
#pragma unroll
  for (int i = 0; i < 8; ++i) {
    p0[i] = expf(l0[i] - m0); s0 += p0[i];
    p1[i] = expf(l1[i] - m1); s1 += p1[i];
  }
#pragma unroll
  for (int m = 1; m < 16; m <<= 1) {
    s0 += __shfl_xor(s0, m);
    s1 += __shfl_xor(s1, m);
  }
  float inv0 = 1.0f / s0, inv1 = 1.0f / s1;
#pragma unroll
  for (int i = 0; i < 8; ++i) { p0[i] *= inv0; p1[i] *= inv1; }

  float o0[16], o1[16];
#pragma unroll
  for (int d = 0; d < 16; ++d) { o0[d] = 0.f; o1[d] = 0.f; }
#pragma unroll
  for (int i = 0; i < 8; ++i) {
    int k = t + 16 * i;
    const float* vr = &vs[k][0];
    float4 v0 = *(const float4*)(vr);
    float4 v1 = *(const float4*)(vr + 4);
    float4 v2 = *(const float4*)(vr + 8);
    float4 v3 = *(const float4*)(vr + 12);
    float pa = p0[i], pb = p1[i];
    o0[0]  = fmaf(pa, v0.x, o0[0]);  o0[1]  = fmaf(pa, v0.y, o0[1]);
    o0[2]  = fmaf(pa, v0.z, o0[2]);  o0[3]  = fmaf(pa, v0.w, o0[3]);
    o0[4]  = fmaf(pa, v1.x, o0[4]);  o0[5]  = fmaf(pa, v1.y, o0[5]);
    o0[6]  = fmaf(pa, v1.z, o0[6]);  o0[7]  = fmaf(pa, v1.w, o0[7]);
    o0[8]  = fmaf(pa, v2.x, o0[8]);  o0[9]  = fmaf(pa, v2.y, o0[9]);
    o0[10] = fmaf(pa, v2.z, o0[10]); o0[11] = fmaf(pa, v2.w, o0[11]);
    o0[12] = fmaf(pa, v3.x, o0[12]); o0[13] = fmaf(pa, v3.y, o0[13]);
    o0[14] = fmaf(pa, v3.z, o0[14]); o0[15] = fmaf(pa, v3.w, o0[15]);
    o1[0]  = fmaf(pb, v0.x, o1[0]);  o1[1]  = fmaf(pb, v0.y, o1[1]);
    o1[2]  = fmaf(pb, v0.z, o1[2]);  o1[3]  = fmaf(pb, v0.w, o1[3]);
    o1[4]  = fmaf(pb, v1.x, o1[4]);  o1[5]  = fmaf(pb, v1.y, o1[5]);
    o1[6]  = fmaf(pb, v1.z, o1[6]);  o1[7]  = fmaf(pb, v1.w, o1[7]);
    o1[8]  = fmaf(pb, v2.x, o1[8]);  o1[9]  = fmaf(pb, v2.y, o1[9]);
    o1[10] = fmaf(pb, v2.z, o1[10]); o1[11] = fmaf(pb, v2.w, o1[11]);
    o1[12] = fmaf(pb, v3.x, o1[12]); o1[13] = fmaf(pb, v3.y, o1[13]);
    o1[14] = fmaf(pb, v3.z, o1[14]); o1[15] = fmaf(pb, v3.w, o1[15]);
  }
#pragma unroll
  for (int d = 0; d < 16; ++d) {
#pragma unroll
    for (int m = 1; m < 16; m <<= 1) {
      o0[d] += __shfl_xor(o0[d], m);
      o1[d] += __shfl_xor(o1[d], m);
    }
  }
  float w0 = 0.f, w1 = 0.f;
#pragma unroll
  for (int d = 0; d < 16; ++d) {
    w0 = (t == d) ? o0[d] : w0;
    w1 = (t == d) ? o1[d] : w1;
  }
  ob[(size_t)(w * NQW + r0) * CC + h * DHH + t] = w0;
  ob[(size_t)(w * NQW + r1) * CC + h * DHH + t] = w1;
}

// ---------------------------------------------------------------------------
// K3: u = (o*g)@Wo + bo ; out = sigmoid(u@W_out + b_out) * u
// 256 blocks x 256 threads, 8 rows/block. R2C2: wave rg -> rows {2rg,2rg+1},
// lane -> 2 cols (float2 W). ds_read count halved vs scalar-W version.
// ---------------------------------------------------------------------------
__global__ __launch_bounds__(256) void k3_out(
    const float* __restrict__ ob_, const float* __restrict__ gb_,
    const float* __restrict__ Wo, const float* __restrict__ bo,
    const float* __restrict__ W_out, const float* __restrict__ b_out,
    float* __restrict__ out)
{
  __shared__ float og[8][132];
  __shared__ float us[8][132];
  const int r0  = blockIdx.x * 8;
  const int tid = threadIdx.x;
  {
    const int r = tid >> 5, t = tid & 31, c0 = t * 4;
    float4 o4 = *(const float4*)(ob_ + (size_t)(r0 + r) * CC + c0);
    float4 g4 = *(const float4*)(gb_ + (size_t)(r0 + r) * CC + c0);
    float4 m4;
    m4.x = o4.x * g4.x; m4.y = o4.y * g4.y;
    m4.z = o4.z * g4.z; m4.w = o4.w * g4.w;
    *(float4*)(&og[r][c0]) = m4;
  }
  __syncthreads();

  const int rg = tid >> 6;        // 0..3 -> rows {2rg, 2rg+1}
  const int cg = tid & 63;
  const int c0 = cg * 2;
  const int ra = rg * 2, rb = rg * 2 + 1;

  float u00 = 0.f, u01 = 0.f, u10 = 0.f, u11 = 0.f;
#pragma unroll 4
  for (int k4 = 0; k4 < 32; ++k4) {
    float4 a0 = *(const float4*)(&og[ra][k4 * 4]);
    float4 a1 = *(const float4*)(&og[rb][k4 * 4]);
#define O1STEP(AX, J) { \
    float2 wv = *(const float2*)(Wo + (k4 * 4 + J) * CC + c0); \
    u00 = fmaf(a0.AX, wv.x, u00); u01 = fmaf(a0.AX, wv.y, u01); \
    u10 = fmaf(a1.AX, wv.x, u10); u11 = fmaf(a1.AX, wv.y, u11); }
    O1STEP(x, 0) O1STEP(y, 1) O1STEP(z, 2) O1STEP(w, 3)
#undef O1STEP
  }
  float2 bov = *(const float2*)(bo + c0);
  u00 += bov.x; u01 += bov.y; u10 += bov.x; u11 += bov.y;
  us[ra][c0]     = u00; us[ra][c0 + 1] = u01;
  us[rb][c0]     = u10; us[rb][c0 + 1] = u11;
  __syncthreads();

  float a00 = 0.f, a01 = 0.f, a10 = 0.f, a11 = 0.f;
#pragma unroll 4
  for (int k4 = 0; k4 < 32; ++k4) {
    float4 a0 = *(const float4*)(&us[ra][k4 * 4]);
    float4 a1 = *(const float4*)(&us[rb][k4 * 4]);
#define O2STEP(AX, J) { \
    float2 wv = *(const float2*)(W_out + (k4 * 4 + J) * CC + c0); \
    a00 = fmaf(a0.AX, wv.x, a00); a01 = fmaf(a0.AX, wv.y, a01); \
    a10 = fmaf(a1.AX, wv.x, a10); a11 = fmaf(a1.AX, wv.y, a11); }
    O2STEP(x, 0) O2STEP(y, 1) O2STEP(z, 2) O2STEP(w, 3)
#undef O2STEP
  }
  float2 b2 = *(const float2*)(b_out + c0);
  float2 ra2, rb2;
  ra2.x = sigm(a00 + b2.x) * u00; ra2.y = sigm(a01 + b2.y) * u01;
  rb2.x = sigm(a10 + b2.x) * u10; rb2.y = sigm(a11 + b2.y) * u11;
  *(float2*)(out + (size_t)(r0 + ra) * CC + c0) = ra2;
  *(float2*)(out + (size_t)(r0 + rb) * CC + c0) = rb2;
}

// ---------------------------------------------------------------------------
extern "C" void kernel_launch(void* const* d_in, const int* in_sizes, int n_in,
                              void* d_out, int out_size, void* d_ws, size_t ws_size,
                              hipStream_t stream) {
  (void)in_sizes; (void)n_in; (void)out_size; (void)ws_size;
  const float* x1      = (const float*)d_in[0];
  const float* x2      = (const float*)d_in[1];
  const float* pair    = (const float*)d_in[2];
  const float* gamma_s = (const float*)d_in[3];
  const float* Wg_ada  = (const float*)d_in[4];
  const float* bg_ada  = (const float*)d_in[5];
  const float* W_skip  = (const float*)d_in[6];
  const float* gamma_p = (const float*)d_in[7];
  const float* beta_p  = (const float*)d_in[8];
  const float* W_pair  = (const float*)d_in[9];
  const float* Wq      = (const float*)d_in[10];
  const float* Wk      = (const float*)d_in[11];
  const float* Wv      = (const float*)d_in[12];
  const float* Wg      = (const float*)d_in[13];
  const float* bg      = (const float*)d_in[14];
  const float* Wo      = (const float*)d_in[15];
  const float* bo      = (const float*)d_in[16];
  const float* W_out   = (const float*)d_in[17];
  const float* b_out   = (const float*)d_in[18];

  float* ws   = (float*)d_ws;
  const size_t NC = (size_t)NTOK * CC;   // 262144
  float* qb   = ws;
  float* kb   = ws + NC;
  float* vb   = ws + 2 * NC;
  float* gb   = ws + 3 * NC;
  float* obuf = ws + 4 * NC;
  float* bias = ws + 5 * NC;             // 64*8*32*128 = 2097152 floats

  k1_fused<<<512, 256, 0, stream>>>(x1, x2, gamma_s, Wg_ada, bg_ada, W_skip,
                                    Wq, Wk, Wv, Wg, bg,
                                    pair, gamma_p, beta_p, W_pair,
                                    qb, kb, vb, gb, bias);
  attn_kernel<<<512, 256, 0, stream>>>(qb, kb, vb, bias, obuf);
  k3_out<<<256, 256, 0, stream>>>(obuf, gb, Wo, bo, W_out, b_out,
                                  (float*)d_out);
}

// Round 8
// 44.101 us; speedup vs baseline: 3.6213x; 1.3342x over previous
//
#include <hip/hip_runtime.h>
#include <math.h>

#define NTOK 2048
#define CC   128
#define CPP  16
#define HH   8
#define DHH  16
#define NQW  32
#define NKW  128
#define PADW 48
#define NBW  64

__device__ __forceinline__ float sigm(float x) { return 1.0f / (1.0f + expf(-x)); }

// ---------------------------------------------------------------------------
// K1: blocks [0,256): LN + adaLN GEMM + all 4 projections for 8 rows, in-LDS.
//     blocks [256,1280): bias (2 tokens each).   (round-5 proven version)
// ---------------------------------------------------------------------------
__global__ __launch_bounds__(256) void k1_fused(
    const float* __restrict__ x1, const float* __restrict__ x2,
    const float* __restrict__ gamma_s,
    const float* __restrict__ Wg_ada, const float* __restrict__ bg_ada,
    const float* __restrict__ W_skip,
    const float* __restrict__ Wq, const float* __restrict__ Wk,
    const float* __restrict__ Wv, const float* __restrict__ Wg,
    const float* __restrict__ bg,
    const float* __restrict__ pair,
    const float* __restrict__ gamma_p, const float* __restrict__ beta_p,
    const float* __restrict__ W_pair,
    float* __restrict__ qb, float* __restrict__ kb,
    float* __restrict__ vb, float* __restrict__ gb,
    float* __restrict__ bias)
{
  const int b   = blockIdx.x;
  const int tid = threadIdx.x;

  if (b < 256) {
    __shared__ float sln[8][132];
    __shared__ float aln[8][132];
    __shared__ float as_[8][132];
    const int r0 = b * 8;

    // ---- LN of 8 rows: 32 lanes per row, float4 per lane ----
    {
      const int r = tid >> 5, t = tid & 31, c0 = t * 4;
      const int row = r0 + r;
      float4 v1 = *(const float4*)(x1 + (size_t)row * CC + c0);
      float4 v2 = *(const float4*)(x2 + (size_t)row * CC + c0);
      float s1 = v1.x + v1.y + v1.z + v1.w;
      float p1 = v1.x * v1.x + v1.y * v1.y + v1.z * v1.z + v1.w * v1.w;
      float s2 = v2.x + v2.y + v2.z + v2.w;
      float p2 = v2.x * v2.x + v2.y * v2.y + v2.z * v2.z + v2.w * v2.w;
#pragma unroll
      for (int m = 1; m < 32; m <<= 1) {
        s1 += __shfl_xor(s1, m); p1 += __shfl_xor(p1, m);
        s2 += __shfl_xor(s2, m); p2 += __shfl_xor(p2, m);
      }
      const float rc = 1.0f / 128.0f;
      float mu1 = s1 * rc, mu2 = s2 * rc;
      float rs1 = rsqrtf(p1 * rc - mu1 * mu1 + 1e-5f);
      float rs2 = rsqrtf(p2 * rc - mu2 * mu2 + 1e-5f);
      float4 gs = *(const float4*)(gamma_s + c0);
      float4 al, sl;
      al.x = (v1.x - mu1) * rs1; al.y = (v1.y - mu1) * rs1;
      al.z = (v1.z - mu1) * rs1; al.w = (v1.w - mu1) * rs1;
      sl.x = (v2.x - mu2) * rs2 * gs.x; sl.y = (v2.y - mu2) * rs2 * gs.y;
      sl.z = (v2.z - mu2) * rs2 * gs.z; sl.w = (v2.w - mu2) * rs2 * gs.w;
      *(float4*)(&aln[r][c0]) = al;
      *(float4*)(&sln[r][c0]) = sl;
    }
    __syncthreads();

    // ---- stage-1 adaLN GEMM: thread (rh=tid>>7, cg=tid&127) -> 4 rows x 1 col
    {
      const int rh = tid >> 7, cg = tid & 127;
      float g0 = 0.f, g1 = 0.f, g2 = 0.f, g3 = 0.f;
      float s0 = 0.f, s1 = 0.f, s2 = 0.f, s3 = 0.f;
#pragma unroll 4
      for (int k4 = 0; k4 < 32; ++k4) {
        float4 a0 = *(const float4*)(&sln[rh * 4 + 0][k4 * 4]);
        float4 a1 = *(const float4*)(&sln[rh * 4 + 1][k4 * 4]);
        float4 a2 = *(const float4*)(&sln[rh * 4 + 2][k4 * 4]);
        float4 a3 = *(const float4*)(&sln[rh * 4 + 3][k4 * 4]);
#define S1STEP(AX, J) { \
        float wg = Wg_ada[(k4 * 4 + J) * CC + cg]; \
        float wk = W_skip[(k4 * 4 + J) * CC + cg]; \
        g0 = fmaf(a0.AX, wg, g0); g1 = fmaf(a1.AX, wg, g1); \
        g2 = fmaf(a2.AX, wg, g2); g3 = fmaf(a3.AX, wg, g3); \
        s0 = fmaf(a0.AX, wk, s0); s1 = fmaf(a1.AX, wk, s1); \
        s2 = fmaf(a2.AX, wk, s2); s3 = fmaf(a3.AX, wk, s3); }
        S1STEP(x, 0) S1STEP(y, 1) S1STEP(z, 2) S1STEP(w, 3)
#undef S1STEP
      }
      float bga = bg_ada[cg];
      as_[rh * 4 + 0][cg] = sigm(g0 + bga) * aln[rh * 4 + 0][cg] + s0;
      as_[rh * 4 + 1][cg] = sigm(g1 + bga) * aln[rh * 4 + 1][cg] + s1;
      as_[rh * 4 + 2][cg] = sigm(g2 + bga) * aln[rh * 4 + 2][cg] + s2;
      as_[rh * 4 + 3][cg] = sigm(g3 + bga) * aln[rh * 4 + 3][cg] + s3;
    }
    __syncthreads();

    // ---- projections: wave m = matrix, lane -> 2 cols, 8 rows ----
    {
      const int m  = tid >> 6;
      const int l  = tid & 63;
      const int c0 = l * 2;
      const float* Wm = (m == 0) ? Wq : (m == 1) ? Wk : (m == 2) ? Wv : Wg;
      float2 c0_ = {0.f, 0.f}, c1_ = {0.f, 0.f}, c2_ = {0.f, 0.f}, c3_ = {0.f, 0.f};
      float2 c4_ = {0.f, 0.f}, c5_ = {0.f, 0.f}, c6_ = {0.f, 0.f}, c7_ = {0.f, 0.f};
#pragma unroll 2
      for (int k4 = 0; k4 < 32; ++k4) {
        float4 ra0 = *(const float4*)(&as_[0][k4 * 4]);
        float4 ra1 = *(const float4*)(&as_[1][k4 * 4]);
        float4 ra2 = *(const float4*)(&as_[2][k4 * 4]);
        float4 ra3 = *(const float4*)(&as_[3][k4 * 4]);
        float4 ra4 = *(const float4*)(&as_[4][k4 * 4]);
        float4 ra5 = *(const float4*)(&as_[5][k4 * 4]);
        float4 ra6 = *(const float4*)(&as_[6][k4 * 4]);
        float4 ra7 = *(const float4*)(&as_[7][k4 * 4]);
#define PJSTEP(AX, J) { \
        float2 wv = *(const float2*)(Wm + (k4 * 4 + J) * CC + c0); \
        c0_.x = fmaf(ra0.AX, wv.x, c0_.x); c0_.y = fmaf(ra0.AX, wv.y, c0_.y); \
        c1_.x = fmaf(ra1.AX, wv.x, c1_.x); c1_.y = fmaf(ra1.AX, wv.y, c1_.y); \
        c2_.x = fmaf(ra2.AX, wv.x, c2_.x); c2_.y = fmaf(ra2.AX, wv.y, c2_.y); \
        c3_.x = fmaf(ra3.AX, wv.x, c3_.x); c3_.y = fmaf(ra3.AX, wv.y, c3_.y); \
        c4_.x = fmaf(ra4.AX, wv.x, c4_.x); c4_.y = fmaf(ra4.AX, wv.y, c4_.y); \
        c5_.x = fmaf(ra5.AX, wv.x, c5_.x); c5_.y = fmaf(ra5.AX, wv.y, c5_.y); \
        c6_.x = fmaf(ra6.AX, wv.x, c6_.x); c6_.y = fmaf(ra6.AX, wv.y, c6_.y); \
        c7_.x = fmaf(ra7.AX, wv.x, c7_.x); c7_.y = fmaf(ra7.AX, wv.y, c7_.y); }
        PJSTEP(x, 0) PJSTEP(y, 1) PJSTEP(z, 2) PJSTEP(w, 3)
#undef PJSTEP
      }
      if (m == 0) {
#define QST(I, CI) { float2 r; r.x = CI.x * 0.25f; r.y = CI.y * 0.25f; \
        *(float2*)(qb + (size_t)(r0 + I) * CC + c0) = r; }
        QST(0, c0_) QST(1, c1_) QST(2, c2_) QST(3, c3_)
        QST(4, c4_) QST(5, c5_) QST(6, c6_) QST(7, c7_)
#undef QST
      } else if (m == 1) {
#define KST(I, CI) *(float2*)(kb + (size_t)(r0 + I) * CC + c0) = CI;
        KST(0, c0_) KST(1, c1_) KST(2, c2_) KST(3, c3_)
        KST(4, c4_) KST(5, c5_) KST(6, c6_) KST(7, c7_)
#undef KST
      } else if (m == 2) {
#define VST(I, CI) *(float2*)(vb + (size_t)(r0 + I) * CC + c0) = CI;
        VST(0, c0_) VST(1, c1_) VST(2, c2_) VST(3, c3_)
        VST(4, c4_) VST(5, c5_) VST(6, c6_) VST(7, c7_)
#undef VST
      } else {
        float2 bgv = *(const float2*)(bg + c0);
#define GST(I, CI) { float2 r; r.x = sigm(CI.x + bgv.x); r.y = sigm(CI.y + bgv.y); \
        *(float2*)(gb + (size_t)(r0 + I) * CC + c0) = r; }
        GST(0, c0_) GST(1, c1_) GST(2, c2_) GST(3, c3_)
        GST(4, c4_) GST(5, c5_) GST(6, c6_) GST(7, c7_)
#undef GST
      }
    }
  } else {
    __shared__ float wp[CPP * HH];
    __shared__ float gp[CPP];
    __shared__ float bp[CPP];
    if (tid < CPP * HH) wp[tid] = W_pair[tid];
    if (tid < CPP) { gp[tid] = gamma_p[tid]; bp[tid] = beta_p[tid]; }
    __syncthreads();

    const int i  = (b - 256) * 2 + (tid >> 7);   // token 0..2047
    const int w  = i >> 5;
    const int qq = i & 31;
    const int k  = tid & 127;
    const int j  = w * NQW + k - PADW;

    float bh[HH];
    if (j >= 0 && j < NTOK) {
      const float* p = pair + ((size_t)i * NTOK + j) * CPP;
      float x[CPP];
#pragma unroll
      for (int u4 = 0; u4 < CPP; u4 += 4) {
        float4 v = *(const float4*)(p + u4);
        x[u4] = v.x; x[u4 + 1] = v.y; x[u4 + 2] = v.z; x[u4 + 3] = v.w;
      }
      float s = 0.f;
#pragma unroll
      for (int c = 0; c < CPP; ++c) s += x[c];
      float mu = s * (1.0f / CPP);
      float vv = 0.f;
#pragma unroll
      for (int c = 0; c < CPP; ++c) { float d = x[c] - mu; vv = fmaf(d, d, vv); }
      float rs = rsqrtf(vv * (1.0f / CPP) + 1e-5f);
#pragma unroll
      for (int h = 0; h < HH; ++h) bh[h] = 0.f;
#pragma unroll
      for (int c = 0; c < CPP; ++c) {
        float y = (x[c] - mu) * rs * gp[c] + bp[c];
#pragma unroll
        for (int h = 0; h < HH; ++h) bh[h] = fmaf(y, wp[c * HH + h], bh[h]);
      }
    } else {
#pragma unroll
      for (int h = 0; h < HH; ++h) bh[h] = -10000.0f;
    }
#pragma unroll
    for (int h = 0; h < HH; ++h)
      bias[((size_t)((w * HH + h) * NQW + qq)) * NKW + k] = bh[h];
  }
}

// ---------------------------------------------------------------------------
// K2: attention, 1024 blocks x 256 threads: block = (window, head, q-half).
// 16 q-rows per block; thread = (qr=tid>>4, t=tid&15) -> 1 q-row, 8 k-cols.
// (round-5 proven version)
// ---------------------------------------------------------------------------
__global__ __launch_bounds__(256) void attn_kernel(
    const float* __restrict__ qb, const float* __restrict__ kb,
    const float* __restrict__ vb, const float* __restrict__ bias,
    float* __restrict__ ob)
{
  __shared__ float qs[16][20];
  __shared__ float ks[NKW][20];
  __shared__ float vs[NKW][20];
  __shared__ float bs[16][132];
  const int u   = blockIdx.x;
  const int w   = u >> 4;
  const int h   = (u >> 1) & 7;
  const int qh  = u & 1;
  const int tid = threadIdx.x;

  if (tid < 64) {
    int qr = tid >> 2, c4 = (tid & 3) * 4;
    float4 v = *(const float4*)(qb + (size_t)(w * NQW + qh * 16 + qr) * CC + h * DHH + c4);
    *(float4*)(&qs[qr][c4]) = v;
  }
  {
    int kr = tid >> 1, c8 = (tid & 1) * 8;
    int j = w * NQW + kr - PADW;
    float4 k0 = make_float4(0.f, 0.f, 0.f, 0.f), k1 = k0, v0 = k0, v1 = k0;
    if (j >= 0 && j < NTOK) {
      const float* kp = kb + (size_t)j * CC + h * DHH + c8;
      const float* vp = vb + (size_t)j * CC + h * DHH + c8;
      k0 = *(const float4*)(kp);     k1 = *(const float4*)(kp + 4);
      v0 = *(const float4*)(vp);     v1 = *(const float4*)(vp + 4);
    }
    *(float4*)(&ks[kr][c8])     = k0;
    *(float4*)(&ks[kr][c8 + 4]) = k1;
    *(float4*)(&vs[kr][c8])     = v0;
    *(float4*)(&vs[kr][c8 + 4]) = v1;
  }
  {
    const float* bt = bias + (size_t)(w * HH + h) * NQW * NKW + (size_t)qh * 16 * NKW;
    int qr = tid >> 4, k8 = (tid & 15) * 8;
    float4 b0 = *(const float4*)(bt + qr * NKW + k8);
    float4 b1 = *(const float4*)(bt + qr * NKW + k8 + 4);
    *(float4*)(&bs[qr][k8])     = b0;
    *(float4*)(&bs[qr][k8 + 4]) = b1;
  }
  __syncthreads();

  const int qr = tid >> 4;   // 0..15
  const int t  = tid & 15;   // 0..15
  float4 q0 = *(float4*)(&qs[qr][0]);
  float4 q1 = *(float4*)(&qs[qr][4]);
  float4 q2 = *(float4*)(&qs[qr][8]);
  float4 q3 = *(float4*)(&qs[qr][12]);

  float l[8];
#pragma unroll
  for (int i = 0; i < 8; ++i) {
    int k = t + 16 * i;
    const float* kr_ = &ks[k][0];
    float4 k0 = *(const float4*)(kr_);
    float4 k1 = *(const float4*)(kr_ + 4);
    float4 k2 = *(const float4*)(kr_ + 8);
    float4 k3 = *(const float4*)(kr_ + 12);
    float d = 0.f;
    d = fmaf(q0.x, k0.x, d); d = fmaf(q0.y, k0.y, d);
    d = fmaf(q0.z, k0.z, d); d = fmaf(q0.w, k0.w, d);
    d = fmaf(q1.x, k1.x, d); d = fmaf(q1.y, k1.y, d);
    d = fmaf(q1.z, k1.z, d); d = fmaf(q1.w, k1.w, d);
    d = fmaf(q2.x, k2.x, d); d = fmaf(q2.y, k2.y, d);
    d = fmaf(q2.z, k2.z, d); d = fmaf(q2.w, k2.w, d);
    d = fmaf(q3.x, k3.x, d); d = fmaf(q3.y, k3.y, d);
    d = fmaf(q3.z, k3.z, d); d = fmaf(q3.w, k3.w, d);
    l[i] = d + bs[qr][k];
  }

  float m0 = l[0];
#pragma unroll
  for (int i = 1; i < 8; ++i) m0 = fmaxf(m0, l[i]);
  m0 = fmaxf(m0, __shfl_xor(m0, 1));
  m0 = fmaxf(m0, __shfl_xor(m0, 2));
  m0 = fmaxf(m0, __shfl_xor(m0, 4));
  m0 = fmaxf(m0, __shfl_xor(m0, 8));
  float s = 0.f;
  float p[8];
#pragma unroll
  for (int i = 0; i < 8; ++i) { p[i] = expf(l[i] - m0); s += p[i]; }
  s += __shfl_xor(s, 1);
  s += __shfl_xor(s, 2);
  s += __shfl_xor(s, 4);
  s += __shfl_xor(s, 8);
  float inv = 1.0f / s;
#pragma unroll
  for (int i = 0; i < 8; ++i) p[i] *= inv;

  float o[16];
#pragma unroll
  for (int d = 0; d < 16; ++d) o[d] = 0.f;
#pragma unroll
  for (int i = 0; i < 8; ++i) {
    int k = t + 16 * i;
    const float* vr = &vs[k][0];
    float4 v0 = *(const float4*)(vr);
    float4 v1 = *(const float4*)(vr + 4);
    float4 v2 = *(const float4*)(vr + 8);
    float4 v3 = *(const float4*)(vr + 12);
    float pa = p[i];
    o[0]  = fmaf(pa, v0.x, o[0]);  o[1]  = fmaf(pa, v0.y, o[1]);
    o[2]  = fmaf(pa, v0.z, o[2]);  o[3]  = fmaf(pa, v0.w, o[3]);
    o[4]  = fmaf(pa, v1.x, o[4]);  o[5]  = fmaf(pa, v1.y, o[5]);
    o[6]  = fmaf(pa, v1.z, o[6]);  o[7]  = fmaf(pa, v1.w, o[7]);
    o[8]  = fmaf(pa, v2.x, o[8]);  o[9]  = fmaf(pa, v2.y, o[9]);
    o[10] = fmaf(pa, v2.z, o[10]); o[11] = fmaf(pa, v2.w, o[11]);
    o[12] = fmaf(pa, v3.x, o[12]); o[13] = fmaf(pa, v3.y, o[13]);
    o[14] = fmaf(pa, v3.z, o[14]); o[15] = fmaf(pa, v3.w, o[15]);
  }
#pragma unroll
  for (int d = 0; d < 16; ++d) {
#pragma unroll
    for (int m = 1; m < 16; m <<= 1) o[d] += __shfl_xor(o[d], m);
  }
  float wsel = 0.f;
#pragma unroll
  for (int d = 0; d < 16; ++d) wsel = (t == d) ? o[d] : wsel;
  ob[(size_t)(w * NQW + qh * 16 + qr) * CC + h * DHH + t] = wsel;
}

// ---------------------------------------------------------------------------
// K3: u = (o*g)@Wo + bo ; out = sigmoid(u@W_out + b_out) * u
// 512 blocks x 256 threads, 4 rows/block (2x TLP vs round-5's 256 blocks).
// thread (rg=tid>>7, cg=tid&127): 2 rows x 1 col; A via row-major LDS b128.
// ---------------------------------------------------------------------------
__global__ __launch_bounds__(256) void k3_out(
    const float* __restrict__ ob_, const float* __restrict__ gb_,
    const float* __restrict__ Wo, const float* __restrict__ bo,
    const float* __restrict__ W_out, const float* __restrict__ b_out,
    float* __restrict__ out)
{
  __shared__ float og[4][132];
  __shared__ float us[4][132];
  const int r0  = blockIdx.x * 4;
  const int tid = threadIdx.x;
  {
    const int r = tid >> 6, t = tid & 63, c0 = t * 2;
    float2 o2 = *(const float2*)(ob_ + (size_t)(r0 + r) * CC + c0);
    float2 g2 = *(const float2*)(gb_ + (size_t)(r0 + r) * CC + c0);
    og[r][c0]     = o2.x * g2.x;
    og[r][c0 + 1] = o2.y * g2.y;
  }
  __syncthreads();

  const int rg = tid >> 7;       // 0..1 -> rows {2rg, 2rg+1}
  const int cg = tid & 127;
  const int ra = rg * 2, rb = rg * 2 + 1;

  float u0 = 0.f, u1 = 0.f;
#pragma unroll 4
  for (int k4 = 0; k4 < 32; ++k4) {
    float4 a0 = *(const float4*)(&og[ra][k4 * 4]);
    float4 a1 = *(const float4*)(&og[rb][k4 * 4]);
#define O1STEP(AX, J) { \
    float wv = Wo[(k4 * 4 + J) * CC + cg]; \
    u0 = fmaf(a0.AX, wv, u0); u1 = fmaf(a1.AX, wv, u1); }
    O1STEP(x, 0) O1STEP(y, 1) O1STEP(z, 2) O1STEP(w, 3)
#undef O1STEP
  }
  float bov = bo[cg];
  u0 += bov; u1 += bov;
  us[ra][cg] = u0;
  us[rb][cg] = u1;
  __syncthreads();

  float a0s = 0.f, a1s = 0.f;
#pragma unroll 4
  for (int k4 = 0; k4 < 32; ++k4) {
    float4 a0 = *(const float4*)(&us[ra][k4 * 4]);
    float4 a1 = *(const float4*)(&us[rb][k4 * 4]);
#define O2STEP(AX, J) { \
    float wv = W_out[(k4 * 4 + J) * CC + cg]; \
    a0s = fmaf(a0.AX, wv, a0s); a1s = fmaf(a1.AX, wv, a1s); }
    O2STEP(x, 0) O2STEP(y, 1) O2STEP(z, 2) O2STEP(w, 3)
#undef O2STEP
  }
  float b2 = b_out[cg];
  out[(size_t)(r0 + ra) * CC + cg] = sigm(a0s + b2) * u0;
  out[(size_t)(r0 + rb) * CC + cg] = sigm(a1s + b2) * u1;
}

// ---------------------------------------------------------------------------
extern "C" void kernel_launch(void* const* d_in, const int* in_sizes, int n_in,
                              void* d_out, int out_size, void* d_ws, size_t ws_size,
                              hipStream_t stream) {
  (void)in_sizes; (void)n_in; (void)out_size; (void)ws_size;
  const float* x1      = (const float*)d_in[0];
  const float* x2      = (const float*)d_in[1];
  const float* pair    = (const float*)d_in[2];
  const float* gamma_s = (const float*)d_in[3];
  const float* Wg_ada  = (const float*)d_in[4];
  const float* bg_ada  = (const float*)d_in[5];
  const float* W_skip  = (const float*)d_in[6];
  const float* gamma_p = (const float*)d_in[7];
  const float* beta_p  = (const float*)d_in[8];
  const float* W_pair  = (const float*)d_in[9];
  const float* Wq      = (const float*)d_in[10];
  const float* Wk      = (const float*)d_in[11];
  const float* Wv      = (const float*)d_in[12];
  const float* Wg      = (const float*)d_in[13];
  const float* bg      = (const float*)d_in[14];
  const float* Wo      = (const float*)d_in[15];
  const float* bo      = (const float*)d_in[16];
  const float* W_out   = (const float*)d_in[17];
  const float* b_out   = (const float*)d_in[18];

  float* ws   = (float*)d_ws;
  const size_t NC = (size_t)NTOK * CC;   // 262144
  float* qb   = ws;
  float* kb   = ws + NC;
  float* vb   = ws + 2 * NC;
  float* gb   = ws + 3 * NC;
  float* obuf = ws + 4 * NC;
  float* bias = ws + 5 * NC;             // 64*8*32*128 = 2097152 floats

  k1_fused<<<1280, 256, 0, stream>>>(x1, x2, gamma_s, Wg_ada, bg_ada, W_skip,
                                     Wq, Wk, Wv, Wg, bg,
                                     pair, gamma_p, beta_p, W_pair,
                                     qb, kb, vb, gb, bias);
  attn_kernel<<<1024, 256, 0, stream>>>(qb, kb, vb, bias, obuf);
  k3_out<<<512, 256, 0, stream>>>(obuf, gb, Wo, bo, W_out, b_out,
                                  (float*)d_out);
}